// Round 1
// baseline (483.795 us; speedup 1.0000x reference)
//
#include <hip/hip_runtime.h>

// Problem constants (fixed by reference)
#define N_NODES 2048
#define EMBED   32
#define B_BATCH 16
#define INP     32
#define OUTC    32
#define NCOL    512   // B*INP columns of X = x^T
#define CHEB_K  3

// ---------------------------------------------------------------------------
// Kernel 1: A[i][j] = softmax_j( exp(-gamma * ||adj_j - adj_i||^2) ) * drop[i][j]
// One block per row i, 256 threads, 8 columns per thread.
// ---------------------------------------------------------------------------
__global__ __launch_bounds__(256) void k_compute_A(
    const float* __restrict__ adj, const float* __restrict__ gammap,
    const float* __restrict__ drop, float* __restrict__ A)
{
    const int i = blockIdx.x;
    const int tid = threadIdx.x;
    __shared__ float ai[EMBED];
    __shared__ float red[256];

    if (tid < EMBED) ai[tid] = adj[i * EMBED + tid];
    __syncthreads();
    const float gamma = gammap[0];

    float s[8];
    float mx = -1e30f;
#pragma unroll
    for (int r = 0; r < 8; r++) {
        const int j = tid + r * 256;
        const float4* aj = (const float4*)(adj + (size_t)j * EMBED);
        float d2 = 0.f;
#pragma unroll
        for (int d4 = 0; d4 < 8; d4++) {
            float4 v = aj[d4];
            float t0 = v.x - ai[d4 * 4 + 0];
            float t1 = v.y - ai[d4 * 4 + 1];
            float t2 = v.z - ai[d4 * 4 + 2];
            float t3 = v.w - ai[d4 * 4 + 3];
            d2 += t0 * t0 + t1 * t1 + t2 * t2 + t3 * t3;
        }
        s[r] = __expf(-gamma * d2);
        mx = fmaxf(mx, s[r]);
    }
    // block-reduce max
    red[tid] = mx; __syncthreads();
    for (int off = 128; off > 0; off >>= 1) {
        if (tid < off) red[tid] = fmaxf(red[tid], red[tid + off]);
        __syncthreads();
    }
    mx = red[0]; __syncthreads();

    float e[8]; float sum = 0.f;
#pragma unroll
    for (int r = 0; r < 8; r++) { e[r] = __expf(s[r] - mx); sum += e[r]; }
    red[tid] = sum; __syncthreads();
    for (int off = 128; off > 0; off >>= 1) {
        if (tid < off) red[tid] += red[tid + off];
        __syncthreads();
    }
    const float inv = 1.0f / red[0];
#pragma unroll
    for (int r = 0; r < 8; r++) {
        const int j = tid + r * 256;
        A[(size_t)i * N_NODES + j] = e[r] * inv * drop[(size_t)i * N_NODES + j];
    }
}

// ---------------------------------------------------------------------------
// GEMM 1 (NT): Y1[m, c] = sum_k A[m,k] * XT[c,k],  XT = x viewed as (512 x 2048)
// 64x64 tile, BK=16, 256 threads, 4x4 micro-tile per thread.
// ---------------------------------------------------------------------------
__global__ __launch_bounds__(256) void k_gemm_nt(
    const float* __restrict__ A, const float* __restrict__ XT,
    float* __restrict__ Y)
{
    const int BM = 64, BN = 64, BK = 16;
    __shared__ float As[BK * BM];   // As[k][m]
    __shared__ float Bs[BK * BN];   // Bs[k][n]
    const int tid = threadIdx.x;
    const int m0 = blockIdx.y * BM;
    const int n0 = blockIdx.x * BN;
    const int tm = tid >> 4, tn = tid & 15;
    const int lr = tid >> 2;            // 0..63
    const int lk = (tid & 3) * 4;       // 0,4,8,12
    float acc[4][4] = {};

    for (int k0 = 0; k0 < N_NODES; k0 += BK) {
        float4 av = *(const float4*)(A  + (size_t)(m0 + lr) * N_NODES + k0 + lk);
        float4 bv = *(const float4*)(XT + (size_t)(n0 + lr) * N_NODES + k0 + lk);
        As[(lk + 0) * BM + lr] = av.x;
        As[(lk + 1) * BM + lr] = av.y;
        As[(lk + 2) * BM + lr] = av.z;
        As[(lk + 3) * BM + lr] = av.w;
        Bs[(lk + 0) * BN + lr] = bv.x;
        Bs[(lk + 1) * BN + lr] = bv.y;
        Bs[(lk + 2) * BN + lr] = bv.z;
        Bs[(lk + 3) * BN + lr] = bv.w;
        __syncthreads();
#pragma unroll
        for (int kk = 0; kk < BK; kk++) {
            const float4 a4 = *(const float4*)(&As[kk * BM + tm * 4]);
            const float4 b4 = *(const float4*)(&Bs[kk * BN + tn * 4]);
            acc[0][0] += a4.x * b4.x; acc[0][1] += a4.x * b4.y; acc[0][2] += a4.x * b4.z; acc[0][3] += a4.x * b4.w;
            acc[1][0] += a4.y * b4.x; acc[1][1] += a4.y * b4.y; acc[1][2] += a4.y * b4.z; acc[1][3] += a4.y * b4.w;
            acc[2][0] += a4.z * b4.x; acc[2][1] += a4.z * b4.y; acc[2][2] += a4.z * b4.z; acc[2][3] += a4.z * b4.w;
            acc[3][0] += a4.w * b4.x; acc[3][1] += a4.w * b4.y; acc[3][2] += a4.w * b4.z; acc[3][3] += a4.w * b4.w;
        }
        __syncthreads();
    }
#pragma unroll
    for (int jm = 0; jm < 4; jm++) {
        const int m = m0 + tm * 4 + jm;
        float4 o4 = make_float4(acc[jm][0], acc[jm][1], acc[jm][2], acc[jm][3]);
        *(float4*)(&Y[(size_t)m * NCOL + n0 + tn * 4]) = o4;
    }
}

// ---------------------------------------------------------------------------
// GEMM 2 (NN) + epilogue: Y2[m,c] = 2*sum_k A[m,k]*Y1[k,c] - XT[c,m]
// ---------------------------------------------------------------------------
__global__ __launch_bounds__(256) void k_gemm_nn_ep(
    const float* __restrict__ A, const float* __restrict__ Bmat,
    const float* __restrict__ XT, float* __restrict__ Y)
{
    const int BM = 64, BN = 64, BK = 16;
    __shared__ float As[BK * BM];   // As[k][m]
    __shared__ float Bs[BK * BN];   // Bs[k][n]
    const int tid = threadIdx.x;
    const int m0 = blockIdx.y * BM;
    const int n0 = blockIdx.x * BN;
    const int tm = tid >> 4, tn = tid & 15;
    const int lr = tid >> 2;            // 0..63 (A rows)
    const int lk = (tid & 3) * 4;       // 0,4,8,12
    const int bk = tid >> 4;            // 0..15 (B rows = k)
    const int bn = (tid & 15) * 4;      // 0..60
    float acc[4][4] = {};

    for (int k0 = 0; k0 < N_NODES; k0 += BK) {
        float4 av = *(const float4*)(A + (size_t)(m0 + lr) * N_NODES + k0 + lk);
        float4 bv = *(const float4*)(Bmat + (size_t)(k0 + bk) * NCOL + n0 + bn);
        As[(lk + 0) * BM + lr] = av.x;
        As[(lk + 1) * BM + lr] = av.y;
        As[(lk + 2) * BM + lr] = av.z;
        As[(lk + 3) * BM + lr] = av.w;
        *(float4*)(&Bs[bk * BN + bn]) = bv;
        __syncthreads();
#pragma unroll
        for (int kk = 0; kk < BK; kk++) {
            const float4 a4 = *(const float4*)(&As[kk * BM + tm * 4]);
            const float4 b4 = *(const float4*)(&Bs[kk * BN + tn * 4]);
            acc[0][0] += a4.x * b4.x; acc[0][1] += a4.x * b4.y; acc[0][2] += a4.x * b4.z; acc[0][3] += a4.x * b4.w;
            acc[1][0] += a4.y * b4.x; acc[1][1] += a4.y * b4.y; acc[1][2] += a4.y * b4.z; acc[1][3] += a4.y * b4.w;
            acc[2][0] += a4.z * b4.x; acc[2][1] += a4.z * b4.y; acc[2][2] += a4.z * b4.z; acc[2][3] += a4.z * b4.w;
            acc[3][0] += a4.w * b4.x; acc[3][1] += a4.w * b4.y; acc[3][2] += a4.w * b4.z; acc[3][3] += a4.w * b4.w;
        }
        __syncthreads();
    }
#pragma unroll
    for (int jm = 0; jm < 4; jm++) {
#pragma unroll
        for (int jn = 0; jn < 4; jn++) {
            const int m = m0 + tm * 4 + jm;
            const int n = n0 + tn * 4 + jn;
            Y[(size_t)m * NCOL + n] = 2.0f * acc[jm][jn] - XT[(size_t)n * N_NODES + m];
        }
    }
}

// ---------------------------------------------------------------------------
// M[b,k,i,d] = sum_n p[n] * adj[n,d] * G_k[n, b*32+i]
// G_0 = X (read from x directly), G_1 = Y1, G_2 = Y2.
// Grid: 48 blocks (b,k), 256 threads; thread owns (i0..i0+3, d).
// ---------------------------------------------------------------------------
__global__ __launch_bounds__(256) void k_reduce_M(
    const float* __restrict__ x, const float* __restrict__ Y1,
    const float* __restrict__ Y2, const float* __restrict__ adj,
    const float* __restrict__ p, float* __restrict__ M)
{
    const int kk = blockIdx.x % CHEB_K;
    const int b  = blockIdx.x / CHEB_K;
    const int tid = threadIdx.x;
    __shared__ float pg[64][33];
    __shared__ float ad[64][33];
    const int d  = tid & 31;
    const int i0 = (tid >> 5) * 4;
    float acc0 = 0.f, acc1 = 0.f, acc2 = 0.f, acc3 = 0.f;

    for (int n0 = 0; n0 < N_NODES; n0 += 64) {
#pragma unroll
        for (int r = 0; r < 8; r++) {
            const int nn = (tid >> 5) + r * 8;
            ad[nn][d] = adj[(size_t)(n0 + nn) * EMBED + d];
        }
        if (kk == 0) {
#pragma unroll
            for (int r = 0; r < 8; r++) {
                const int nn = tid & 63;
                const int i = (tid >> 6) + r * 4;
                pg[nn][i] = p[n0 + nn] * x[(size_t)(b * INP + i) * N_NODES + n0 + nn];
            }
        } else {
            const float* __restrict__ G = (kk == 1) ? Y1 : Y2;
#pragma unroll
            for (int r = 0; r < 8; r++) {
                const int nn = (tid >> 5) + r * 8;
                const int i = tid & 31;
                pg[nn][i] = p[n0 + nn] * G[(size_t)(n0 + nn) * NCOL + b * INP + i];
            }
        }
        __syncthreads();
#pragma unroll 8
        for (int nn = 0; nn < 64; nn++) {
            const float a = ad[nn][d];
            acc0 += pg[nn][i0 + 0] * a;
            acc1 += pg[nn][i0 + 1] * a;
            acc2 += pg[nn][i0 + 2] * a;
            acc3 += pg[nn][i0 + 3] * a;
        }
        __syncthreads();
    }
    float* Mb = M + (size_t)(b * CHEB_K + kk) * INP * EMBED;
    Mb[(i0 + 0) * EMBED + d] = acc0;
    Mb[(i0 + 1) * EMBED + d] = acc1;
    Mb[(i0 + 2) * EMBED + d] = acc2;
    Mb[(i0 + 3) * EMBED + d] = acc3;
}

// ---------------------------------------------------------------------------
// q[d] = sum_n p[n] * adj[n,d]   (single block)
// ---------------------------------------------------------------------------
__global__ __launch_bounds__(256) void k_q(
    const float* __restrict__ adj, const float* __restrict__ p,
    float* __restrict__ q)
{
    __shared__ float red[256];
    const int d = threadIdx.x & 31;
    const int g = threadIdx.x >> 5;   // 0..7
    float s = 0.f;
    for (int n = g; n < N_NODES; n += 8) s += p[n] * adj[(size_t)n * EMBED + d];
    red[threadIdx.x] = s;
    __syncthreads();
    if (g == 0) {
        float t = 0.f;
        for (int gg = 0; gg < 8; gg++) t += red[gg * 32 + d];
        q[d] = t;
    }
}

// ---------------------------------------------------------------------------
// res[b,o] = sum_{k,i,d} M[b,k,i,d]*Wp[d,k,i,o] + sum_d q[d]*bp[d,o] + proj_b
// Grid: 16 blocks (b), 256 threads: o = tid&31, chunk c = tid>>5 over 3072.
// ---------------------------------------------------------------------------
__global__ __launch_bounds__(256) void k_final(
    const float* __restrict__ M, const float* __restrict__ W,
    const float* __restrict__ bp, const float* __restrict__ q,
    const float* __restrict__ pb, float* __restrict__ out)
{
    const int b = blockIdx.x;
    const int o = threadIdx.x & 31;
    const int c = threadIdx.x >> 5;    // 0..7
    __shared__ float part[8][32];
    const float* Mb = M + (size_t)b * (CHEB_K * INP * EMBED);
    float acc = 0.f;
    for (int t = c * 384; t < (c + 1) * 384; t++) {
        const int k = t >> 10;          // t = k*1024 + i*32 + d
        const int i = (t >> 5) & 31;
        const int d = t & 31;
        acc += Mb[t] * W[((size_t)(d * CHEB_K + k) * INP + i) * OUTC + o];
    }
    part[c][o] = acc;
    __syncthreads();
    if (c == 0) {
        float s = 0.f;
        for (int cc = 0; cc < 8; cc++) s += part[cc][o];
        for (int d = 0; d < EMBED; d++) s += q[d] * bp[d * OUTC + o];
        s += pb[0];
        out[b * OUTC + o] = s;
    }
}

// ---------------------------------------------------------------------------
extern "C" void kernel_launch(void* const* d_in, const int* in_sizes, int n_in,
                              void* d_out, int out_size, void* d_ws, size_t ws_size,
                              hipStream_t stream)
{
    const float* x     = (const float*)d_in[0];  // (B, INP, N)
    const float* adj   = (const float*)d_in[1];  // (N, EMBED)
    const float* gamma = (const float*)d_in[2];  // scalar
    const float* Wp    = (const float*)d_in[3];  // (EMBED, K, INP, OUT)
    const float* bp    = (const float*)d_in[4];  // (EMBED, OUT)
    const float* pw    = (const float*)d_in[5];  // (1, N)
    const float* pb    = (const float*)d_in[6];  // (1,)
    const float* drop  = (const float*)d_in[7];  // (N, N)
    float* out = (float*)d_out;

    // workspace layout (floats): A(4M) | Y1(1M) | Y2(1M) | M(49152) | q(32)  ~25.4 MB
    float* ws = (float*)d_ws;
    float* A  = ws;
    float* Y1 = A  + (size_t)N_NODES * N_NODES;
    float* Y2 = Y1 + (size_t)N_NODES * NCOL;
    float* M  = Y2 + (size_t)N_NODES * NCOL;
    float* q  = M  + (size_t)B_BATCH * CHEB_K * INP * EMBED;

    k_compute_A<<<N_NODES, 256, 0, stream>>>(adj, gamma, drop, A);

    dim3 g1(NCOL / 64, N_NODES / 64);   // 8 x 32 = 256 blocks
    k_gemm_nt<<<g1, 256, 0, stream>>>(A, x, Y1);
    k_gemm_nn_ep<<<g1, 256, 0, stream>>>(A, Y1, x, Y2);

    k_reduce_M<<<B_BATCH * CHEB_K, 256, 0, stream>>>(x, Y1, Y2, adj, pw, M);
    k_q<<<1, 256, 0, stream>>>(adj, pw, q);
    k_final<<<B_BATCH, 256, 0, stream>>>(M, Wp, bp, q, pb, out);
}

// Round 2
// 316.868 us; speedup vs baseline: 1.5268x; 1.5268x over previous
//
#include <hip/hip_runtime.h>

// Problem constants (fixed by reference)
#define N_NODES 2048
#define EMBED   32
#define B_BATCH 16
#define INP     32
#define OUTC    32
#define NCOL    512   // B*INP columns of X' (X'[c, n] = x[b, i, n], c = b*32+i)
#define CHEB_K  3

// ---------------------------------------------------------------------------
// Algebraic restructure (R1): output only consumes G_k = supports[k] @ X
// through M_k[d,c] = sum_n p[n]*adj[n,d]*G_k[n,c] = (U^T G_k)[d,c],
// U[n,d] = p[n]*adj[n,d].  Pushing U^T through the Chebyshev recursion:
//   M_0 = U^T X,  M_1 = V1^T X (V1 = A^T U),  M_2 = 2*V2^T X - M_0 (V2 = A^T V1)
// -> two thin (2048x2048)^T x (2048x32) products instead of two
//    (2048x2048)x(2048x512) GEMMs.  ~10x fewer FLOPs, no 25MB intermediates.
// ---------------------------------------------------------------------------

// ---------------------------------------------------------------------------
// Kernel 1: A[i][j] = softmax_j( exp(-gamma * ||adj_j - adj_i||^2) ) * drop[i][j]
// One block per row i, 256 threads, 8 columns per thread.
// ---------------------------------------------------------------------------
__global__ __launch_bounds__(256) void k_compute_A(
    const float* __restrict__ adj, const float* __restrict__ gammap,
    const float* __restrict__ drop, float* __restrict__ A)
{
    const int i = blockIdx.x;
    const int tid = threadIdx.x;
    __shared__ float ai[EMBED];
    __shared__ float red[256];

    if (tid < EMBED) ai[tid] = adj[i * EMBED + tid];
    __syncthreads();
    const float gamma = gammap[0];

    float s[8];
    float mx = -1e30f;
#pragma unroll
    for (int r = 0; r < 8; r++) {
        const int j = tid + r * 256;
        const float4* aj = (const float4*)(adj + (size_t)j * EMBED);
        float d2 = 0.f;
#pragma unroll
        for (int d4 = 0; d4 < 8; d4++) {
            float4 v = aj[d4];
            float t0 = v.x - ai[d4 * 4 + 0];
            float t1 = v.y - ai[d4 * 4 + 1];
            float t2 = v.z - ai[d4 * 4 + 2];
            float t3 = v.w - ai[d4 * 4 + 3];
            d2 += t0 * t0 + t1 * t1 + t2 * t2 + t3 * t3;
        }
        s[r] = __expf(-gamma * d2);
        mx = fmaxf(mx, s[r]);
    }
    red[tid] = mx; __syncthreads();
    for (int off = 128; off > 0; off >>= 1) {
        if (tid < off) red[tid] = fmaxf(red[tid], red[tid + off]);
        __syncthreads();
    }
    mx = red[0]; __syncthreads();

    float e[8]; float sum = 0.f;
#pragma unroll
    for (int r = 0; r < 8; r++) { e[r] = __expf(s[r] - mx); sum += e[r]; }
    red[tid] = sum; __syncthreads();
    for (int off = 128; off > 0; off >>= 1) {
        if (tid < off) red[tid] += red[tid + off];
        __syncthreads();
    }
    const float inv = 1.0f / red[0];
#pragma unroll
    for (int r = 0; r < 8; r++) {
        const int j = tid + r * 256;
        A[(size_t)i * N_NODES + j] = e[r] * inv * drop[(size_t)i * N_NODES + j];
    }
}

// ---------------------------------------------------------------------------
// U[m,d] = p[m] * adj[m,d]
// ---------------------------------------------------------------------------
__global__ __launch_bounds__(256) void k_aux(
    const float* __restrict__ adj, const float* __restrict__ p,
    float* __restrict__ U)
{
    const int idx = blockIdx.x * 256 + threadIdx.x;   // 0 .. 65535
    U[idx] = p[idx >> 5] * adj[idx];
}

// ---------------------------------------------------------------------------
// q[d] = sum_n p[n] * adj[n,d]   (single block)
// ---------------------------------------------------------------------------
__global__ __launch_bounds__(256) void k_q(
    const float* __restrict__ adj, const float* __restrict__ p,
    float* __restrict__ q)
{
    __shared__ float red[256];
    const int d = threadIdx.x & 31;
    const int g = threadIdx.x >> 5;   // 0..7
    float s = 0.f;
    for (int n = g; n < N_NODES; n += 8) s += p[n] * adj[(size_t)n * EMBED + d];
    red[threadIdx.x] = s;
    __syncthreads();
    if (g == 0) {
        float t = 0.f;
        for (int gg = 0; gg < 8; gg++) t += red[gg * 32 + d];
        q[d] = t;
    }
}

// ---------------------------------------------------------------------------
// Vp[chunk][n][d] partial of V[n,d] = sum_m A[m,n] * Vin[m,d]
// grid: (16 n-tiles of 128, 16 m-chunks of 128), 256 threads.
// tid&127 -> n within tile; tid>>7 -> which 16-d half.
// ---------------------------------------------------------------------------
__global__ __launch_bounds__(256) void k_atv(
    const float* __restrict__ A, const float* __restrict__ Vin,
    float* __restrict__ Vp)
{
    __shared__ float Us[128 * 32];
    const int tid = threadIdx.x;
    const int n  = blockIdx.x * 128 + (tid & 127);
    const int dh = (tid >> 7) * 16;          // 0 or 16
    const int m0 = blockIdx.y * 128;

#pragma unroll
    for (int r = 0; r < 16; r++) {
        const int idx = r * 256 + tid;
        Us[idx] = Vin[m0 * EMBED + idx];
    }
    __syncthreads();

    float4 a0 = {}, a1 = {}, a2 = {}, a3 = {};
    for (int mm = 0; mm < 128; mm++) {
        const float a = A[(size_t)(m0 + mm) * N_NODES + n];
        const float4* u4 = (const float4*)(&Us[mm * 32 + dh]);
        float4 u0 = u4[0], u1 = u4[1], u2 = u4[2], u3 = u4[3];
        a0.x += a * u0.x; a0.y += a * u0.y; a0.z += a * u0.z; a0.w += a * u0.w;
        a1.x += a * u1.x; a1.y += a * u1.y; a1.z += a * u1.z; a1.w += a * u1.w;
        a2.x += a * u2.x; a2.y += a * u2.y; a2.z += a * u2.z; a2.w += a * u2.w;
        a3.x += a * u3.x; a3.y += a * u3.y; a3.z += a * u3.z; a3.w += a * u3.w;
    }
    float4* out = (float4*)(Vp + (size_t)blockIdx.y * (N_NODES * EMBED)
                               + (size_t)n * EMBED + dh);
    out[0] = a0; out[1] = a1; out[2] = a2; out[3] = a3;
}

// ---------------------------------------------------------------------------
// V[idx] = sum over 16 chunks of Vp
// ---------------------------------------------------------------------------
__global__ __launch_bounds__(256) void k_vred(
    const float* __restrict__ Vp, float* __restrict__ V)
{
    const int idx = blockIdx.x * 256 + threadIdx.x;   // 0..65535
    float s = 0.f;
#pragma unroll
    for (int c = 0; c < 16; c++) s += Vp[(size_t)c * (N_NODES * EMBED) + idx];
    V[idx] = s;
}

// ---------------------------------------------------------------------------
// M_k[d,c] = sum_n Vk[n,d] * X'[c,n]   for k=0,1,2 fused (one x read).
// V0 = U, V1, V2.  M layout: M[k][d][c], c = b*32+i.
// grid: 64 blocks (c-tiles of 8), 256 threads = 8c x 32d.
// ---------------------------------------------------------------------------
__global__ __launch_bounds__(256) void k_M(
    const float* __restrict__ XT, const float* __restrict__ V0,
    const float* __restrict__ V1, const float* __restrict__ V2,
    float* __restrict__ M)
{
    __shared__ float xs[8][64];
    __shared__ float vs[3][64 * 32];
    const int tid = threadIdx.x;
    const int c = tid >> 5;
    const int d = tid & 31;
    const int c0 = blockIdx.x * 8;
    float a0 = 0.f, a1 = 0.f, a2 = 0.f;

    for (int n0 = 0; n0 < N_NODES; n0 += 64) {
#pragma unroll
        for (int r = 0; r < 2; r++) {
            const int idx = r * 256 + tid;          // 0..511
            xs[idx >> 6][idx & 63] = XT[(size_t)(c0 + (idx >> 6)) * N_NODES + n0 + (idx & 63)];
        }
#pragma unroll
        for (int r = 0; r < 8; r++) {
            const int idx = r * 256 + tid;          // 0..2047
            vs[0][idx] = V0[(size_t)n0 * EMBED + idx];
            vs[1][idx] = V1[(size_t)n0 * EMBED + idx];
            vs[2][idx] = V2[(size_t)n0 * EMBED + idx];
        }
        __syncthreads();
#pragma unroll 8
        for (int nn = 0; nn < 64; nn++) {
            const float xv = xs[c][nn];
            a0 += xv * vs[0][nn * 32 + d];
            a1 += xv * vs[1][nn * 32 + d];
            a2 += xv * vs[2][nn * 32 + d];
        }
        __syncthreads();
    }
    M[0 * (EMBED * NCOL) + d * NCOL + c0 + c] = a0;
    M[1 * (EMBED * NCOL) + d * NCOL + c0 + c] = a1;
    M[2 * (EMBED * NCOL) + d * NCOL + c0 + c] = a2;
}

// ---------------------------------------------------------------------------
// out[b,o] = sum_{d,i} [ M0*(W0-W2) + M1*W1 + 2*M2p*W2 ] + sum_d q[d]*bp[d,o] + pb
// grid: 16 blocks (b), 256 threads: o = tid&31, chunk over (d,i).
// ---------------------------------------------------------------------------
__global__ __launch_bounds__(256) void k_final(
    const float* __restrict__ M, const float* __restrict__ W,
    const float* __restrict__ bp, const float* __restrict__ q,
    const float* __restrict__ pb, float* __restrict__ out)
{
    const int b = blockIdx.x;
    const int o = threadIdx.x & 31;
    const int ch = threadIdx.x >> 5;    // 0..7
    __shared__ float part[8][32];
    float acc = 0.f;
    for (int t = ch * 128; t < (ch + 1) * 128; t++) {   // t over (d,i), 1024
        const int d = t >> 5;
        const int i = t & 31;
        const int c = b * INP + i;
        const float m0 = M[0 * (EMBED * NCOL) + d * NCOL + c];
        const float m1 = M[1 * (EMBED * NCOL) + d * NCOL + c];
        const float m2 = M[2 * (EMBED * NCOL) + d * NCOL + c];
        const float w0 = W[((size_t)(d * CHEB_K + 0) * INP + i) * OUTC + o];
        const float w1 = W[((size_t)(d * CHEB_K + 1) * INP + i) * OUTC + o];
        const float w2 = W[((size_t)(d * CHEB_K + 2) * INP + i) * OUTC + o];
        acc += m0 * w0 + m1 * w1 + (2.0f * m2 - m0) * w2;
    }
    part[ch][o] = acc;
    __syncthreads();
    if (ch == 0) {
        float s = 0.f;
        for (int cc = 0; cc < 8; cc++) s += part[cc][o];
        for (int d = 0; d < EMBED; d++) s += q[d] * bp[d * OUTC + o];
        s += pb[0];
        out[b * OUTC + o] = s;
    }
}

// ---------------------------------------------------------------------------
extern "C" void kernel_launch(void* const* d_in, const int* in_sizes, int n_in,
                              void* d_out, int out_size, void* d_ws, size_t ws_size,
                              hipStream_t stream)
{
    const float* x     = (const float*)d_in[0];  // (B, INP, N) -> X'[c, n]
    const float* adj   = (const float*)d_in[1];  // (N, EMBED)
    const float* gamma = (const float*)d_in[2];  // scalar
    const float* Wp    = (const float*)d_in[3];  // (EMBED, K, INP, OUT)
    const float* bp    = (const float*)d_in[4];  // (EMBED, OUT)
    const float* pw    = (const float*)d_in[5];  // (1, N)
    const float* pb    = (const float*)d_in[6];  // (1,)
    const float* drop  = (const float*)d_in[7];  // (N, N)
    float* out = (float*)d_out;

    // workspace (floats): A(4M) | Vp(1M) | U(64K) | V1(64K) | V2(64K) | M(48K) | q(32)
    float* ws = (float*)d_ws;
    float* A  = ws;
    float* Vp = A  + (size_t)N_NODES * N_NODES;
    float* U  = Vp + (size_t)16 * N_NODES * EMBED;
    float* V1 = U  + (size_t)N_NODES * EMBED;
    float* V2 = V1 + (size_t)N_NODES * EMBED;
    float* M  = V2 + (size_t)N_NODES * EMBED;
    float* q  = M  + (size_t)CHEB_K * EMBED * NCOL;

    k_aux<<<N_NODES * EMBED / 256, 256, 0, stream>>>(adj, pw, U);
    k_compute_A<<<N_NODES, 256, 0, stream>>>(adj, gamma, drop, A);
    k_q<<<1, 256, 0, stream>>>(adj, pw, q);

    dim3 gatv(16, 16);
    k_atv<<<gatv, 256, 0, stream>>>(A, U, Vp);      // V1 partials
    k_vred<<<N_NODES * EMBED / 256, 256, 0, stream>>>(Vp, V1);
    k_atv<<<gatv, 256, 0, stream>>>(A, V1, Vp);     // V2 partials
    k_vred<<<N_NODES * EMBED / 256, 256, 0, stream>>>(Vp, V2);

    k_M<<<NCOL / 8, 256, 0, stream>>>(x, U, V1, V2, M);
    k_final<<<B_BATCH, 256, 0, stream>>>(M, Wp, bp, q, pb, out);
}

// Round 3
// 249.139 us; speedup vs baseline: 1.9419x; 1.2719x over previous
//
#include <hip/hip_runtime.h>

// Problem constants (fixed by reference)
#define N_NODES 2048
#define EMBED   32
#define B_BATCH 16
#define INP     32
#define OUTC    32
#define NCOL    512
#define CHEB_K  3

// R2: Gram-matrix restructure of the kernel graph computation.
//   dist(i,j) = |a_i|^2 + |a_j|^2 - 2 a_i.a_j  ->  tiled GEMM-shaped k_gram
//   S[i][j] = exp(-gamma*dist) stored once; row softmax stats in k_stats;
//   A = exp(S-mx)*inv*drop is built ON THE FLY inside the two thin A^T V
//   products (k_v) - A never materialized.

// ---------------------------------------------------------------------------
// k_gram: 64x64 tiles of S = exp(-gamma * dist). grid (32 jt, 32 it).
// Also writes per-tile row-max partials Pmax[jt][i].
// ---------------------------------------------------------------------------
__global__ __launch_bounds__(256) void k_gram(
    const float* __restrict__ adj, const float* __restrict__ gammap,
    float* __restrict__ S, float* __restrict__ Pmax)
{
    __shared__ float ai[64][33];
    __shared__ float aj[64][33];
    __shared__ float nI[64], nJ[64];
    __shared__ float rm[64][17];
    const int tid = threadIdx.x;
    const int j0 = blockIdx.x * 64;
    const int i0 = blockIdx.y * 64;
    const float gamma = gammap[0];

#pragma unroll
    for (int r = 0; r < 8; r++) {
        const int idx = r * 256 + tid;           // 0..2047
        ai[idx >> 5][idx & 31] = adj[(size_t)(i0 + (idx >> 5)) * EMBED + (idx & 31)];
        aj[idx >> 5][idx & 31] = adj[(size_t)(j0 + (idx >> 5)) * EMBED + (idx & 31)];
    }
    __syncthreads();
    if (tid < 64) {
        float s = 0.f;
#pragma unroll
        for (int k = 0; k < 32; k++) { float v = ai[tid][k]; s += v * v; }
        nI[tid] = s;
    } else if (tid < 128) {
        float s = 0.f;
#pragma unroll
        for (int k = 0; k < 32; k++) { float v = aj[tid - 64][k]; s += v * v; }
        nJ[tid - 64] = s;
    }
    __syncthreads();

    const int ti = tid >> 4;        // 0..15 row group
    const int tj = tid & 15;        // 0..15 col group
    float acc[4][4] = {};
#pragma unroll
    for (int k = 0; k < 32; k++) {
        float a0 = ai[ti * 4 + 0][k], a1 = ai[ti * 4 + 1][k];
        float a2 = ai[ti * 4 + 2][k], a3 = ai[ti * 4 + 3][k];
        float b0 = aj[tj * 4 + 0][k], b1 = aj[tj * 4 + 1][k];
        float b2 = aj[tj * 4 + 2][k], b3 = aj[tj * 4 + 3][k];
        acc[0][0] += a0 * b0; acc[0][1] += a0 * b1; acc[0][2] += a0 * b2; acc[0][3] += a0 * b3;
        acc[1][0] += a1 * b0; acc[1][1] += a1 * b1; acc[1][2] += a1 * b2; acc[1][3] += a1 * b3;
        acc[2][0] += a2 * b0; acc[2][1] += a2 * b1; acc[2][2] += a2 * b2; acc[2][3] += a2 * b3;
        acc[3][0] += a3 * b0; acc[3][1] += a3 * b1; acc[3][2] += a3 * b2; acc[3][3] += a3 * b3;
    }
    float sv[4][4];
#pragma unroll
    for (int r = 0; r < 4; r++) {
        const float ni = nI[ti * 4 + r];
        float vmax = -1e30f;
#pragma unroll
        for (int c = 0; c < 4; c++) {
            const float dist = ni + nJ[tj * 4 + c] - 2.f * acc[r][c];
            const float s = __expf(-gamma * dist);
            sv[r][c] = s;
            vmax = fmaxf(vmax, s);
        }
        *(float4*)(&S[(size_t)(i0 + ti * 4 + r) * N_NODES + j0 + tj * 4]) =
            make_float4(sv[r][0], sv[r][1], sv[r][2], sv[r][3]);
        rm[ti * 4 + r][tj] = vmax;
    }
    __syncthreads();
    if (tid < 64) {
        float m = -1e30f;
#pragma unroll
        for (int t = 0; t < 16; t++) m = fmaxf(m, rm[tid][t]);
        Pmax[(size_t)blockIdx.x * N_NODES + i0 + tid] = m;
    }
}

// ---------------------------------------------------------------------------
// k_stats: blocks 0..2047: row mx + inv softmax denom.  blocks 2048..2055: U.
// block 2056: q[d] = sum_n p[n]*adj[n,d].
// ---------------------------------------------------------------------------
__global__ __launch_bounds__(256) void k_stats(
    const float* __restrict__ S, const float* __restrict__ Pmax,
    const float* __restrict__ adj, const float* __restrict__ p,
    float* __restrict__ rowmx, float* __restrict__ rowinv,
    float* __restrict__ U, float* __restrict__ q)
{
    const int bid = blockIdx.x;
    const int tid = threadIdx.x;
    if (bid < N_NODES) {
        const int i = bid;
        float mx = -1e30f;
#pragma unroll
        for (int t = 0; t < 32; t++) mx = fmaxf(mx, Pmax[(size_t)t * N_NODES + i]);
        __shared__ float red[256];
        float sum = 0.f;
#pragma unroll
        for (int r = 0; r < 8; r++)
            sum += __expf(S[(size_t)i * N_NODES + r * 256 + tid] - mx);
        red[tid] = sum; __syncthreads();
        for (int off = 128; off > 0; off >>= 1) {
            if (tid < off) red[tid] += red[tid + off];
            __syncthreads();
        }
        if (tid == 0) { rowmx[i] = mx; rowinv[i] = 1.0f / red[0]; }
    } else if (bid < N_NODES + 8) {
        const int base = (bid - N_NODES) * 8192;
#pragma unroll
        for (int r = 0; r < 32; r++) {
            const int idx = base + r * 256 + tid;
            U[idx] = p[idx >> 5] * adj[idx];
        }
    } else {
        __shared__ float red[256];
        const int d = tid & 31;
        const int g = tid >> 5;
        float s = 0.f;
        for (int n = g; n < N_NODES; n += 8) s += p[n] * adj[(size_t)n * EMBED + d];
        red[tid] = s; __syncthreads();
        if (g == 0) {
            float t = 0.f;
            for (int gg = 0; gg < 8; gg++) t += red[gg * 32 + d];
            q[d] = t;
        }
    }
}

// ---------------------------------------------------------------------------
// k_v: Vp[chunk][n][d] partial of V[n,d] = sum_m A[m,n]*Vin[m,d],
// A[m,n] = exp(S[m,n]-mx[m])*inv[m]*drop[m,n] computed on the fly.
// grid (16 n-tiles x 128, 16 m-chunks x 128), 256 threads.
// ---------------------------------------------------------------------------
__global__ __launch_bounds__(256) void k_v(
    const float* __restrict__ S, const float* __restrict__ drop,
    const float* __restrict__ rowmx, const float* __restrict__ rowinv,
    const float* __restrict__ Vin, float* __restrict__ Vp)
{
    __shared__ float Us[128 * 32];
    __shared__ float mxs[128], ivs[128];
    const int tid = threadIdx.x;
    const int n  = blockIdx.x * 128 + (tid & 127);
    const int dh = (tid >> 7) * 16;          // 0 or 16
    const int m0 = blockIdx.y * 128;

#pragma unroll
    for (int r = 0; r < 16; r++) {
        const int idx = r * 256 + tid;
        Us[idx] = Vin[m0 * EMBED + idx];
    }
    if (tid < 128) { mxs[tid] = rowmx[m0 + tid]; ivs[tid] = rowinv[m0 + tid]; }
    __syncthreads();

    float4 a0 = {}, a1 = {}, a2 = {}, a3 = {};
    for (int mm = 0; mm < 128; mm++) {
        const float s  = S[(size_t)(m0 + mm) * N_NODES + n];
        const float dm = drop[(size_t)(m0 + mm) * N_NODES + n];
        const float a  = __expf(s - mxs[mm]) * ivs[mm] * dm;
        const float4* u4 = (const float4*)(&Us[mm * 32 + dh]);
        float4 u0 = u4[0], u1 = u4[1], u2 = u4[2], u3 = u4[3];
        a0.x += a * u0.x; a0.y += a * u0.y; a0.z += a * u0.z; a0.w += a * u0.w;
        a1.x += a * u1.x; a1.y += a * u1.y; a1.z += a * u1.z; a1.w += a * u1.w;
        a2.x += a * u2.x; a2.y += a * u2.y; a2.z += a * u2.z; a2.w += a * u2.w;
        a3.x += a * u3.x; a3.y += a * u3.y; a3.z += a * u3.z; a3.w += a * u3.w;
    }
    float4* out = (float4*)(Vp + (size_t)blockIdx.y * (N_NODES * EMBED)
                               + (size_t)n * EMBED + dh);
    out[0] = a0; out[1] = a1; out[2] = a2; out[3] = a3;
}

__global__ __launch_bounds__(256) void k_vred(
    const float* __restrict__ Vp, float* __restrict__ V)
{
    const int idx = blockIdx.x * 256 + threadIdx.x;   // 0..65535
    float s = 0.f;
#pragma unroll
    for (int c = 0; c < 16; c++) s += Vp[(size_t)c * (N_NODES * EMBED) + idx];
    V[idx] = s;
}

// ---------------------------------------------------------------------------
// k_M: partials of M_k[d,c] = sum_n Vk[n,d] * X'[c,n], all k fused.
// grid (16 c-tiles x 32, 32 n-chunks x 64), 256 threads.
// thread: d = tid>>3 (0..31), cg = tid&7 -> c = cg*4+cc.
// ---------------------------------------------------------------------------
__global__ __launch_bounds__(256) void k_M(
    const float* __restrict__ XT, const float* __restrict__ V0,
    const float* __restrict__ V1, const float* __restrict__ V2,
    float* __restrict__ Mp)
{
    __shared__ float xs[32][64];
    __shared__ float vs[3][64 * 32];
    const int tid = threadIdx.x;
    const int c0 = blockIdx.x * 32;
    const int n0 = blockIdx.y * 64;
    const int d  = tid >> 3;
    const int cg = (tid & 7) * 4;

#pragma unroll
    for (int r = 0; r < 8; r++) {
        const int idx = r * 256 + tid;        // 0..2047
        xs[idx >> 6][idx & 63] = XT[(size_t)(c0 + (idx >> 6)) * N_NODES + n0 + (idx & 63)];
        vs[0][idx] = V0[(size_t)n0 * EMBED + idx];
        vs[1][idx] = V1[(size_t)n0 * EMBED + idx];
        vs[2][idx] = V2[(size_t)n0 * EMBED + idx];
    }
    __syncthreads();

    float acc[3][4] = {};
#pragma unroll 4
    for (int nn = 0; nn < 64; nn++) {
        const float v0 = vs[0][nn * 32 + d];
        const float v1 = vs[1][nn * 32 + d];
        const float v2 = vs[2][nn * 32 + d];
#pragma unroll
        for (int cc = 0; cc < 4; cc++) {
            const float xv = xs[cg + cc][nn];
            acc[0][cc] += xv * v0;
            acc[1][cc] += xv * v1;
            acc[2][cc] += xv * v2;
        }
    }
#pragma unroll
    for (int k = 0; k < 3; k++) {
        float* dst = Mp + ((size_t)(blockIdx.y * 3 + k) * EMBED + d) * NCOL + c0 + cg;
        *(float4*)dst = make_float4(acc[k][0], acc[k][1], acc[k][2], acc[k][3]);
    }
}

__global__ __launch_bounds__(256) void k_Mred(
    const float* __restrict__ Mp, float* __restrict__ M)
{
    const int idx = blockIdx.x * 256 + threadIdx.x;   // 0..49151
    float s = 0.f;
#pragma unroll
    for (int c = 0; c < 32; c++) s += Mp[(size_t)c * (CHEB_K * EMBED * NCOL) + idx];
    M[idx] = s;
}

// ---------------------------------------------------------------------------
// out[b,o] = sum_{d,i} [ M0*(W0-W2) + M1*W1 + 2*M2*W2 ] + sum_d q[d]*bp[d,o] + pb
// ---------------------------------------------------------------------------
__global__ __launch_bounds__(256) void k_final(
    const float* __restrict__ M, const float* __restrict__ W,
    const float* __restrict__ bp, const float* __restrict__ q,
    const float* __restrict__ pb, float* __restrict__ out)
{
    const int b = blockIdx.x;
    const int o = threadIdx.x & 31;
    const int ch = threadIdx.x >> 5;    // 0..7
    __shared__ float part[8][32];
    float acc = 0.f;
    for (int t = ch * 128; t < (ch + 1) * 128; t++) {   // t over (d,i)
        const int d = t >> 5;
        const int i = t & 31;
        const int c = b * INP + i;
        const float m0 = M[0 * (EMBED * NCOL) + d * NCOL + c];
        const float m1 = M[1 * (EMBED * NCOL) + d * NCOL + c];
        const float m2 = M[2 * (EMBED * NCOL) + d * NCOL + c];
        const float w0 = W[((size_t)(d * CHEB_K + 0) * INP + i) * OUTC + o];
        const float w1 = W[((size_t)(d * CHEB_K + 1) * INP + i) * OUTC + o];
        const float w2 = W[((size_t)(d * CHEB_K + 2) * INP + i) * OUTC + o];
        acc += m0 * w0 + m1 * w1 + (2.0f * m2 - m0) * w2;
    }
    part[ch][o] = acc;
    __syncthreads();
    if (ch == 0) {
        float s = 0.f;
        for (int cc = 0; cc < 8; cc++) s += part[cc][o];
        for (int d = 0; d < EMBED; d++) s += q[d] * bp[d * OUTC + o];
        s += pb[0];
        out[b * OUTC + o] = s;
    }
}

// ---------------------------------------------------------------------------
extern "C" void kernel_launch(void* const* d_in, const int* in_sizes, int n_in,
                              void* d_out, int out_size, void* d_ws, size_t ws_size,
                              hipStream_t stream)
{
    const float* x     = (const float*)d_in[0];
    const float* adj   = (const float*)d_in[1];
    const float* gamma = (const float*)d_in[2];
    const float* Wp    = (const float*)d_in[3];
    const float* bp    = (const float*)d_in[4];
    const float* pw    = (const float*)d_in[5];
    const float* pb    = (const float*)d_in[6];
    const float* drop  = (const float*)d_in[7];
    float* out = (float*)d_out;

    float* ws = (float*)d_ws;
    float* S     = ws;                                          // 4M
    float* Pmax  = S     + (size_t)N_NODES * N_NODES;           // 64K
    float* rowmx = Pmax  + (size_t)32 * N_NODES;                // 2K
    float* rowiv = rowmx + N_NODES;                             // 2K
    float* U     = rowiv + N_NODES;                             // 64K
    float* q     = U     + (size_t)N_NODES * EMBED;             // 32
    float* V1    = q     + 64;                                  // 64K
    float* V2    = V1    + (size_t)N_NODES * EMBED;             // 64K
    float* Vp    = V2    + (size_t)N_NODES * EMBED;             // 1M
    float* Mp    = Vp    + (size_t)16 * N_NODES * EMBED;        // 1.5M
    float* M     = Mp    + (size_t)32 * CHEB_K * EMBED * NCOL;  // 48K

    k_gram<<<dim3(32, 32), 256, 0, stream>>>(adj, gamma, S, Pmax);
    k_stats<<<N_NODES + 9, 256, 0, stream>>>(S, Pmax, adj, pw, rowmx, rowiv, U, q);

    dim3 gv(16, 16);
    k_v<<<gv, 256, 0, stream>>>(S, drop, rowmx, rowiv, U, Vp);
    k_vred<<<N_NODES * EMBED / 256, 256, 0, stream>>>(Vp, V1);
    k_v<<<gv, 256, 0, stream>>>(S, drop, rowmx, rowiv, V1, Vp);
    k_vred<<<N_NODES * EMBED / 256, 256, 0, stream>>>(Vp, V2);

    k_M<<<dim3(16, 32), 256, 0, stream>>>(x, U, V1, V2, Mp);
    k_Mred<<<CHEB_K * EMBED * NCOL / 256, 256, 0, stream>>>(Mp, M);
    k_final<<<B_BATCH, 256, 0, stream>>>(M, Wp, bp, q, pb, out);
}

// Round 4
// 232.478 us; speedup vs baseline: 2.0810x; 1.0717x over previous
//
#include <hip/hip_runtime.h>

// Problem constants (fixed by reference)
#define N_NODES 2048
#define EMBED   32
#define B_BATCH 16
#define INP     32
#define OUTC    32
#define NCOL    512
#define CHEB_K  3

// R3: softmax logits t = exp(-gamma*dist) are in (0,1] -> exp(t) in [1,e]:
// max-subtraction is unnecessary (softmax is shift-invariant, no overflow).
// k_gram directly emits Ehat = exp(exp(-gamma*dist))*drop + row-sum partials;
// A[m,n] = Ehat[m,n]*inv[m] with inv folded into the thin operand.

// ---------------------------------------------------------------------------
// k_pre: blocks 0..7: nrm[i] = |adj_i|^2 and U[i,d] = p[i]*adj[i,d] (256 rows
// per block). block 8: q[d] = sum_n p[n]*adj[n,d].
// ---------------------------------------------------------------------------
__global__ __launch_bounds__(256) void k_pre(
    const float* __restrict__ adj, const float* __restrict__ p,
    float* __restrict__ nrm, float* __restrict__ U, float* __restrict__ q)
{
    const int tid = threadIdx.x;
    if (blockIdx.x < 8) {
        __shared__ float adjL[256][33];
        const int base = blockIdx.x * 256;
#pragma unroll
        for (int r = 0; r < 32; r++) {
            const int idx = r * 256 + tid;          // 0..8191
            adjL[idx >> 5][idx & 31] = adj[(size_t)base * EMBED + idx];
        }
        __syncthreads();
        float s = 0.f;
#pragma unroll
        for (int k = 0; k < 32; k++) { const float v = adjL[tid][k]; s += v * v; }
        nrm[base + tid] = s;
#pragma unroll
        for (int r = 0; r < 32; r++) {
            const int idx = r * 256 + tid;
            U[(size_t)base * EMBED + idx] = p[base + (idx >> 5)] * adjL[idx >> 5][idx & 31];
        }
    } else {
        __shared__ float red[256];
        const int d = tid & 31;
        const int g = tid >> 5;
        float s = 0.f;
        for (int n = g; n < N_NODES; n += 8) s += p[n] * adj[(size_t)n * EMBED + d];
        red[tid] = s; __syncthreads();
        if (g == 0) {
            float t = 0.f;
            for (int gg = 0; gg < 8; gg++) t += red[gg * 32 + d];
            q[d] = t;
        }
    }
}

// ---------------------------------------------------------------------------
// k_gram: 64x64 tiles. Ehat[i][j] = exp(exp(-gamma*dist(i,j))) * drop[i][j],
// Psum[jt][i] = sum_{j in tile jt} exp(exp(-gamma*dist)).  grid (32 jt, 32 it).
// ---------------------------------------------------------------------------
__global__ __launch_bounds__(256) void k_gram(
    const float* __restrict__ adj, const float* __restrict__ gammap,
    const float* __restrict__ nrm, const float* __restrict__ drop,
    float* __restrict__ Ehat, float* __restrict__ Psum)
{
    __shared__ float ai[64][36];     // [row][k], float4 along k
    __shared__ float ajT[32][68];    // [k][col], float4 along col
    __shared__ float nI[64], nJ[64];
    __shared__ float rm[64][17];
    const int tid = threadIdx.x;
    const int j0 = blockIdx.x * 64;
    const int i0 = blockIdx.y * 64;
    const float gamma = gammap[0];

#pragma unroll
    for (int r = 0; r < 8; r++) {
        const int idx = r * 256 + tid;           // 0..2047
        ai[idx >> 5][idx & 31]  = adj[(size_t)(i0 + (idx >> 5)) * EMBED + (idx & 31)];
        ajT[idx & 31][idx >> 5] = adj[(size_t)(j0 + (idx >> 5)) * EMBED + (idx & 31)];
    }
    if (tid < 64)       nI[tid]      = nrm[i0 + tid];
    else if (tid < 128) nJ[tid - 64] = nrm[j0 + tid - 64];
    __syncthreads();

    const int ti = tid >> 4;        // 0..15 -> rows ti*4..+3
    const int tj = tid & 15;        // 0..15 -> cols tj*4..+3
    float acc[4][4] = {};
#pragma unroll
    for (int k4 = 0; k4 < 8; k4++) {
        float4 a4[4], b4[4];
#pragma unroll
        for (int r = 0; r < 4; r++) a4[r] = *(const float4*)&ai[ti * 4 + r][k4 * 4];
#pragma unroll
        for (int kk = 0; kk < 4; kk++) b4[kk] = *(const float4*)&ajT[k4 * 4 + kk][tj * 4];
#pragma unroll
        for (int r = 0; r < 4; r++) {
            acc[r][0] += a4[r].x * b4[0].x + a4[r].y * b4[1].x + a4[r].z * b4[2].x + a4[r].w * b4[3].x;
            acc[r][1] += a4[r].x * b4[0].y + a4[r].y * b4[1].y + a4[r].z * b4[2].y + a4[r].w * b4[3].y;
            acc[r][2] += a4[r].x * b4[0].z + a4[r].y * b4[1].z + a4[r].z * b4[2].z + a4[r].w * b4[3].z;
            acc[r][3] += a4[r].x * b4[0].w + a4[r].y * b4[1].w + a4[r].z * b4[2].w + a4[r].w * b4[3].w;
        }
    }
#pragma unroll
    for (int r = 0; r < 4; r++) {
        const int i = i0 + ti * 4 + r;
        const float ni = nI[ti * 4 + r];
        float e[4];
#pragma unroll
        for (int c = 0; c < 4; c++) {
            const float dist = ni + nJ[tj * 4 + c] - 2.f * acc[r][c];
            e[c] = __expf(__expf(-gamma * dist));
        }
        rm[ti * 4 + r][tj] = e[0] + e[1] + e[2] + e[3];
        const float4 dr = *(const float4*)&drop[(size_t)i * N_NODES + j0 + tj * 4];
        *(float4*)(&Ehat[(size_t)i * N_NODES + j0 + tj * 4]) =
            make_float4(e[0] * dr.x, e[1] * dr.y, e[2] * dr.z, e[3] * dr.w);
    }
    __syncthreads();
    if (tid < 64) {
        float s = 0.f;
#pragma unroll
        for (int t = 0; t < 16; t++) s += rm[tid][t];
        Psum[(size_t)blockIdx.x * N_NODES + i0 + tid] = s;
    }
}

// ---------------------------------------------------------------------------
// k_inv: inv[i] = 1/sum_t Psum[t][i]; U'[i,d] = inv[i]*U[i,d].  8 blocks.
// ---------------------------------------------------------------------------
__global__ __launch_bounds__(256) void k_inv(
    const float* __restrict__ Psum, const float* __restrict__ U,
    float* __restrict__ inv, float* __restrict__ Up)
{
    __shared__ float invL[256];
    const int tid = threadIdx.x;
    const int base = blockIdx.x * 256;
    float s = 0.f;
#pragma unroll
    for (int t = 0; t < 32; t++) s += Psum[(size_t)t * N_NODES + base + tid];
    const float iv = 1.0f / s;
    inv[base + tid] = iv;
    invL[tid] = iv;
    __syncthreads();
#pragma unroll
    for (int r = 0; r < 32; r++) {
        const int idx = r * 256 + tid;          // 0..8191
        Up[(size_t)base * EMBED + idx] = invL[idx >> 5] * U[(size_t)base * EMBED + idx];
    }
}

// ---------------------------------------------------------------------------
// k_v: Vp[chunk][n][d] partial of V[n,d] = sum_m Ehat[m,n] * Vin[m,d]
// (Vin already has inv folded in).  grid (16 n-tiles x 128, 32 m-chunks x 64).
// ---------------------------------------------------------------------------
__global__ __launch_bounds__(256) void k_v(
    const float* __restrict__ Ehat, const float* __restrict__ Vin,
    float* __restrict__ Vp)
{
    __shared__ float Us[64 * 32];
    const int tid = threadIdx.x;
    const int n  = blockIdx.x * 128 + (tid & 127);
    const int dh = (tid >> 7) * 16;          // 0 or 16
    const int m0 = blockIdx.y * 64;

#pragma unroll
    for (int r = 0; r < 8; r++) {
        const int idx = r * 256 + tid;       // 0..2047
        Us[idx] = Vin[(size_t)m0 * EMBED + idx];
    }
    __syncthreads();

    float4 a0 = {}, a1 = {}, a2 = {}, a3 = {};
    for (int mm = 0; mm < 64; mm++) {
        const float a = Ehat[(size_t)(m0 + mm) * N_NODES + n];
        const float4* u4 = (const float4*)(&Us[mm * 32 + dh]);
        const float4 u0 = u4[0], u1 = u4[1], u2 = u4[2], u3 = u4[3];
        a0.x += a * u0.x; a0.y += a * u0.y; a0.z += a * u0.z; a0.w += a * u0.w;
        a1.x += a * u1.x; a1.y += a * u1.y; a1.z += a * u1.z; a1.w += a * u1.w;
        a2.x += a * u2.x; a2.y += a * u2.y; a2.z += a * u2.z; a2.w += a * u2.w;
        a3.x += a * u3.x; a3.y += a * u3.y; a3.z += a * u3.z; a3.w += a * u3.w;
    }
    float4* out = (float4*)(Vp + (size_t)blockIdx.y * (N_NODES * EMBED)
                               + (size_t)n * EMBED + dh);
    out[0] = a0; out[1] = a1; out[2] = a2; out[3] = a3;
}

// ---------------------------------------------------------------------------
// k_vred: V[idx] = sum over 32 chunks; optionally Vprime = inv[row]*V.
// ---------------------------------------------------------------------------
__global__ __launch_bounds__(256) void k_vred(
    const float* __restrict__ Vp, const float* __restrict__ inv,
    float* __restrict__ V, float* __restrict__ Vprime, int writePrime)
{
    const int idx = blockIdx.x * 256 + threadIdx.x;   // 0..65535
    float s = 0.f;
#pragma unroll
    for (int c = 0; c < 32; c++) s += Vp[(size_t)c * (N_NODES * EMBED) + idx];
    V[idx] = s;
    if (writePrime) Vprime[idx] = inv[idx >> 5] * s;
}

// ---------------------------------------------------------------------------
// k_M: partials of M_k[d,c] = sum_n Vk[n,d] * X'[c,n], all k fused.
// grid (16 c-tiles x 32, 32 n-chunks x 64), 256 threads.
// ---------------------------------------------------------------------------
__global__ __launch_bounds__(256) void k_M(
    const float* __restrict__ XT, const float* __restrict__ V0,
    const float* __restrict__ V1, const float* __restrict__ V2,
    float* __restrict__ Mp)
{
    __shared__ float xs[32][65];
    __shared__ float vs[3][64 * 32];
    const int tid = threadIdx.x;
    const int c0 = blockIdx.x * 32;
    const int n0 = blockIdx.y * 64;
    const int d  = tid >> 3;
    const int cg = (tid & 7) * 4;

#pragma unroll
    for (int r = 0; r < 8; r++) {
        const int idx = r * 256 + tid;        // 0..2047
        xs[idx >> 6][idx & 63] = XT[(size_t)(c0 + (idx >> 6)) * N_NODES + n0 + (idx & 63)];
        vs[0][idx] = V0[(size_t)n0 * EMBED + idx];
        vs[1][idx] = V1[(size_t)n0 * EMBED + idx];
        vs[2][idx] = V2[(size_t)n0 * EMBED + idx];
    }
    __syncthreads();

    float acc[3][4] = {};
#pragma unroll 4
    for (int nn = 0; nn < 64; nn++) {
        const float v0 = vs[0][nn * 32 + d];
        const float v1 = vs[1][nn * 32 + d];
        const float v2 = vs[2][nn * 32 + d];
#pragma unroll
        for (int cc = 0; cc < 4; cc++) {
            const float xv = xs[cg + cc][nn];
            acc[0][cc] += xv * v0;
            acc[1][cc] += xv * v1;
            acc[2][cc] += xv * v2;
        }
    }
#pragma unroll
    for (int k = 0; k < 3; k++) {
        float* dst = Mp + ((size_t)(blockIdx.y * 3 + k) * EMBED + d) * NCOL + c0 + cg;
        *(float4*)dst = make_float4(acc[k][0], acc[k][1], acc[k][2], acc[k][3]);
    }
}

// ---------------------------------------------------------------------------
// k_final: fused Mp-chunk reduction + epilogue.
// out[b,o] = sum_{d,i} [ M0*(W0-W2) + M1*W1 + 2*M2*W2 ] + sum_d q[d]*bp[d,o] + pb
// ---------------------------------------------------------------------------
__global__ __launch_bounds__(256) void k_final(
    const float* __restrict__ Mp, const float* __restrict__ W,
    const float* __restrict__ bp, const float* __restrict__ q,
    const float* __restrict__ pb, float* __restrict__ out)
{
    const int b = blockIdx.x;
    const int tid = threadIdx.x;
    __shared__ float Ms[96][32];    // [k*32+d][i]
    for (int e = tid; e < 3072; e += 256) {
        const int kd = e >> 5;       // 0..95
        const int i  = e & 31;
        const int k  = kd >> 5;
        const int d  = kd & 31;
        float s = 0.f;
#pragma unroll
        for (int ch = 0; ch < 32; ch++)
            s += Mp[((size_t)(ch * 3 + k) * EMBED + d) * NCOL + b * INP + i];
        Ms[kd][i] = s;
    }
    __syncthreads();

    const int o  = tid & 31;
    const int ch = tid >> 5;    // 0..7
    __shared__ float part[8][32];
    float acc = 0.f;
    for (int t = ch * 128; t < (ch + 1) * 128; t++) {   // t over (d,i)
        const int d = t >> 5;
        const int i = t & 31;
        const float m0 = Ms[d][i];
        const float m1 = Ms[32 + d][i];
        const float m2 = Ms[64 + d][i];
        const float w0 = W[((size_t)(d * CHEB_K + 0) * INP + i) * OUTC + o];
        const float w1 = W[((size_t)(d * CHEB_K + 1) * INP + i) * OUTC + o];
        const float w2 = W[((size_t)(d * CHEB_K + 2) * INP + i) * OUTC + o];
        acc += m0 * w0 + m1 * w1 + (2.0f * m2 - m0) * w2;
    }
    part[ch][o] = acc;
    __syncthreads();
    if (ch == 0) {
        float s = 0.f;
        for (int cc = 0; cc < 8; cc++) s += part[cc][o];
        for (int d = 0; d < EMBED; d++) s += q[d] * bp[d * OUTC + o];
        s += pb[0];
        out[b * OUTC + o] = s;
    }
}

// ---------------------------------------------------------------------------
extern "C" void kernel_launch(void* const* d_in, const int* in_sizes, int n_in,
                              void* d_out, int out_size, void* d_ws, size_t ws_size,
                              hipStream_t stream)
{
    const float* x     = (const float*)d_in[0];
    const float* adj   = (const float*)d_in[1];
    const float* gamma = (const float*)d_in[2];
    const float* Wp    = (const float*)d_in[3];
    const float* bp    = (const float*)d_in[4];
    const float* pw    = (const float*)d_in[5];
    const float* pb    = (const float*)d_in[6];
    const float* drop  = (const float*)d_in[7];
    float* out = (float*)d_out;

    float* ws = (float*)d_ws;
    float* Ehat = ws;                                        // 4,194,304
    float* Vp   = Ehat + (size_t)N_NODES * N_NODES;          // 2,097,152 (aliased Mp)
    float* Mp   = Vp;
    float* Psum = Vp   + (size_t)32 * N_NODES * EMBED;       // 65,536
    float* nrm  = Psum + (size_t)32 * N_NODES;               // 2048
    float* inv  = nrm  + N_NODES;                            // 2048
    float* U    = inv  + N_NODES;                            // 65,536
    float* Up   = U    + (size_t)N_NODES * EMBED;            // 65,536
    float* V1   = Up   + (size_t)N_NODES * EMBED;            // 65,536
    float* V1p  = V1   + (size_t)N_NODES * EMBED;            // 65,536
    float* V2   = V1p  + (size_t)N_NODES * EMBED;            // 65,536
    float* q    = V2   + (size_t)N_NODES * EMBED;            // 64

    k_pre<<<9, 256, 0, stream>>>(adj, pw, nrm, U, q);
    k_gram<<<dim3(32, 32), 256, 0, stream>>>(adj, gamma, nrm, drop, Ehat, Psum);
    k_inv<<<8, 256, 0, stream>>>(Psum, U, inv, Up);

    dim3 gv(16, 32);
    k_v<<<gv, 256, 0, stream>>>(Ehat, Up, Vp);
    k_vred<<<256, 256, 0, stream>>>(Vp, inv, V1, V1p, 1);
    k_v<<<gv, 256, 0, stream>>>(Ehat, V1p, Vp);
    k_vred<<<256, 256, 0, stream>>>(Vp, inv, V2, V2, 0);

    k_M<<<dim3(16, 32), 256, 0, stream>>>(x, U, V1, V2, Mp);
    k_final<<<B_BATCH, 256, 0, stream>>>(Mp, Wp, bp, q, pb, out);
}

// Round 5
// 174.226 us; speedup vs baseline: 2.7768x; 1.3343x over previous
//
#include <hip/hip_runtime.h>

// Problem constants (fixed by reference)
#define N_NODES 2048
#define EMBED   32
#define B_BATCH 16
#define INP     32
#define OUTC    32
#define NCOL    512
#define CHEB_K  3

// R4: removed the ~58us single-block latency loop (q computed as a wide
// reduction of U inside k_inv); k_pre deleted (k_gram computes its own tile
// norms); 8 dispatches total.

// ---------------------------------------------------------------------------
// k_gram: 64x64 tiles. Ehat[i][j] = exp(exp(-gamma*dist(i,j))) * drop[i][j],
// Psum[jt][i] = sum_{j in tile jt} exp(exp(-gamma*dist)).  grid (32 jt, 32 it).
// dist(i,j) = |a_i|^2 + |a_j|^2 - 2 a_i.a_j ; norms computed from LDS tiles.
// ---------------------------------------------------------------------------
__global__ __launch_bounds__(256) void k_gram(
    const float* __restrict__ adj, const float* __restrict__ gammap,
    const float* __restrict__ drop,
    float* __restrict__ Ehat, float* __restrict__ Psum)
{
    __shared__ float ai[64][36];     // [row][k], float4 along k
    __shared__ float ajT[32][68];    // [k][col], float4 along col
    __shared__ float nI[64], nJ[64];
    __shared__ float rm[64][17];
    const int tid = threadIdx.x;
    const int j0 = blockIdx.x * 64;
    const int i0 = blockIdx.y * 64;
    const float gamma = gammap[0];

#pragma unroll
    for (int r = 0; r < 8; r++) {
        const int idx = r * 256 + tid;           // 0..2047
        ai[idx >> 5][idx & 31]  = adj[(size_t)(i0 + (idx >> 5)) * EMBED + (idx & 31)];
        ajT[idx & 31][idx >> 5] = adj[(size_t)(j0 + (idx >> 5)) * EMBED + (idx & 31)];
    }
    __syncthreads();
    if (tid < 64) {
        float s = 0.f;
#pragma unroll
        for (int k = 0; k < 32; k++) { const float v = ai[tid][k]; s += v * v; }
        nI[tid] = s;
    } else if (tid < 128) {
        const int col = tid - 64;
        float s = 0.f;
#pragma unroll
        for (int k = 0; k < 32; k++) { const float v = ajT[k][col]; s += v * v; }
        nJ[col] = s;
    }
    __syncthreads();

    const int ti = tid >> 4;        // 0..15 -> rows ti*4..+3
    const int tj = tid & 15;        // 0..15 -> cols tj*4..+3
    float acc[4][4] = {};
#pragma unroll
    for (int k4 = 0; k4 < 8; k4++) {
        float4 a4[4], b4[4];
#pragma unroll
        for (int r = 0; r < 4; r++) a4[r] = *(const float4*)&ai[ti * 4 + r][k4 * 4];
#pragma unroll
        for (int kk = 0; kk < 4; kk++) b4[kk] = *(const float4*)&ajT[k4 * 4 + kk][tj * 4];
#pragma unroll
        for (int r = 0; r < 4; r++) {
            acc[r][0] += a4[r].x * b4[0].x + a4[r].y * b4[1].x + a4[r].z * b4[2].x + a4[r].w * b4[3].x;
            acc[r][1] += a4[r].x * b4[0].y + a4[r].y * b4[1].y + a4[r].z * b4[2].y + a4[r].w * b4[3].y;
            acc[r][2] += a4[r].x * b4[0].z + a4[r].y * b4[1].z + a4[r].z * b4[2].z + a4[r].w * b4[3].z;
            acc[r][3] += a4[r].x * b4[0].w + a4[r].y * b4[1].w + a4[r].z * b4[2].w + a4[r].w * b4[3].w;
        }
    }
#pragma unroll
    for (int r = 0; r < 4; r++) {
        const int i = i0 + ti * 4 + r;
        const float ni = nI[ti * 4 + r];
        float e[4];
#pragma unroll
        for (int c = 0; c < 4; c++) {
            const float dist = ni + nJ[tj * 4 + c] - 2.f * acc[r][c];
            e[c] = __expf(__expf(-gamma * dist));
        }
        rm[ti * 4 + r][tj] = e[0] + e[1] + e[2] + e[3];
        const float4 dr = *(const float4*)&drop[(size_t)i * N_NODES + j0 + tj * 4];
        *(float4*)(&Ehat[(size_t)i * N_NODES + j0 + tj * 4]) =
            make_float4(e[0] * dr.x, e[1] * dr.y, e[2] * dr.z, e[3] * dr.w);
    }
    __syncthreads();
    if (tid < 64) {
        float s = 0.f;
#pragma unroll
        for (int t = 0; t < 16; t++) s += rm[tid][t];
        Psum[(size_t)blockIdx.x * N_NODES + i0 + tid] = s;
    }
}

// ---------------------------------------------------------------------------
// k_inv: 8 blocks x 256 rows. inv[i] = 1/sum_t Psum[t][i];
// U[i,d] = p[i]*adj[i,d]; Up = inv*U; qpart[blk][d] = sum_{rows} U[i,d].
// ---------------------------------------------------------------------------
__global__ __launch_bounds__(256) void k_inv(
    const float* __restrict__ Psum, const float* __restrict__ adj,
    const float* __restrict__ p,
    float* __restrict__ inv, float* __restrict__ U, float* __restrict__ Up,
    float* __restrict__ qpart)
{
    __shared__ float invL[256];
    __shared__ float uL[256][33];
    __shared__ float red[256];
    const int tid = threadIdx.x;
    const int base = blockIdx.x * 256;

    float s = 0.f;
#pragma unroll
    for (int t = 0; t < 32; t++) s += Psum[(size_t)t * N_NODES + base + tid];
    const float iv = 1.0f / s;
    inv[base + tid] = iv;
    invL[tid] = iv;
    __syncthreads();

#pragma unroll
    for (int r = 0; r < 32; r++) {
        const int idx = r * 256 + tid;          // 0..8191
        const int row = idx >> 5;
        const float u = p[base + row] * adj[(size_t)base * EMBED + idx];
        uL[row][idx & 31] = u;
        U[(size_t)base * EMBED + idx]  = u;
        Up[(size_t)base * EMBED + idx] = invL[row] * u;
    }
    __syncthreads();

    // qpart[blk][d] = sum over 256 rows of uL[row][d]
    const int d = tid & 31;
    const int g = tid >> 5;       // 0..7
    float qs = 0.f;
#pragma unroll
    for (int r = 0; r < 32; r++) qs += uL[g * 32 + r][d];
    red[tid] = qs;
    __syncthreads();
    if (g == 0) {
        float t = 0.f;
#pragma unroll
        for (int gg = 0; gg < 8; gg++) t += red[gg * 32 + d];
        qpart[blockIdx.x * EMBED + d] = t;
    }
}

// ---------------------------------------------------------------------------
// k_v: Vp[chunk][n][d] partial of V[n,d] = sum_m Ehat[m,n] * Vin[m,d]
// (Vin already has inv folded in).  grid (16 n-tiles x 128, 32 m-chunks x 64).
// ---------------------------------------------------------------------------
__global__ __launch_bounds__(256) void k_v(
    const float* __restrict__ Ehat, const float* __restrict__ Vin,
    float* __restrict__ Vp)
{
    __shared__ float Us[64 * 32];
    const int tid = threadIdx.x;
    const int n  = blockIdx.x * 128 + (tid & 127);
    const int dh = (tid >> 7) * 16;          // 0 or 16
    const int m0 = blockIdx.y * 64;

#pragma unroll
    for (int r = 0; r < 8; r++) {
        const int idx = r * 256 + tid;       // 0..2047
        Us[idx] = Vin[(size_t)m0 * EMBED + idx];
    }
    __syncthreads();

    float4 a0 = {}, a1 = {}, a2 = {}, a3 = {};
    for (int mm = 0; mm < 64; mm++) {
        const float a = Ehat[(size_t)(m0 + mm) * N_NODES + n];
        const float4* u4 = (const float4*)(&Us[mm * 32 + dh]);
        const float4 u0 = u4[0], u1 = u4[1], u2 = u4[2], u3 = u4[3];
        a0.x += a * u0.x; a0.y += a * u0.y; a0.z += a * u0.z; a0.w += a * u0.w;
        a1.x += a * u1.x; a1.y += a * u1.y; a1.z += a * u1.z; a1.w += a * u1.w;
        a2.x += a * u2.x; a2.y += a * u2.y; a2.z += a * u2.z; a2.w += a * u2.w;
        a3.x += a * u3.x; a3.y += a * u3.y; a3.z += a * u3.z; a3.w += a * u3.w;
    }
    float4* out = (float4*)(Vp + (size_t)blockIdx.y * (N_NODES * EMBED)
                               + (size_t)n * EMBED + dh);
    out[0] = a0; out[1] = a1; out[2] = a2; out[3] = a3;
}

// ---------------------------------------------------------------------------
// k_vred: V[idx] = sum over 32 chunks; optionally Vprime = inv[row]*V.
// ---------------------------------------------------------------------------
__global__ __launch_bounds__(256) void k_vred(
    const float* __restrict__ Vp, const float* __restrict__ inv,
    float* __restrict__ V, float* __restrict__ Vprime, int writePrime)
{
    const int idx = blockIdx.x * 256 + threadIdx.x;   // 0..65535
    float s = 0.f;
#pragma unroll
    for (int c = 0; c < 32; c++) s += Vp[(size_t)c * (N_NODES * EMBED) + idx];
    V[idx] = s;
    if (writePrime) Vprime[idx] = inv[idx >> 5] * s;
}

// ---------------------------------------------------------------------------
// k_M: partials of M_k[d,c] = sum_n Vk[n,d] * X'[c,n], all k fused.
// grid (16 c-tiles x 32, 32 n-chunks x 64), 256 threads.
// ---------------------------------------------------------------------------
__global__ __launch_bounds__(256) void k_M(
    const float* __restrict__ XT, const float* __restrict__ V0,
    const float* __restrict__ V1, const float* __restrict__ V2,
    float* __restrict__ Mp)
{
    __shared__ float xs[32][65];
    __shared__ float vs[3][64 * 32];
    const int tid = threadIdx.x;
    const int c0 = blockIdx.x * 32;
    const int n0 = blockIdx.y * 64;
    const int d  = tid >> 3;
    const int cg = (tid & 7) * 4;

#pragma unroll
    for (int r = 0; r < 8; r++) {
        const int idx = r * 256 + tid;        // 0..2047
        xs[idx >> 6][idx & 63] = XT[(size_t)(c0 + (idx >> 6)) * N_NODES + n0 + (idx & 63)];
        vs[0][idx] = V0[(size_t)n0 * EMBED + idx];
        vs[1][idx] = V1[(size_t)n0 * EMBED + idx];
        vs[2][idx] = V2[(size_t)n0 * EMBED + idx];
    }
    __syncthreads();

    float acc[3][4] = {};
#pragma unroll 4
    for (int nn = 0; nn < 64; nn++) {
        const float v0 = vs[0][nn * 32 + d];
        const float v1 = vs[1][nn * 32 + d];
        const float v2 = vs[2][nn * 32 + d];
#pragma unroll
        for (int cc = 0; cc < 4; cc++) {
            const float xv = xs[cg + cc][nn];
            acc[0][cc] += xv * v0;
            acc[1][cc] += xv * v1;
            acc[2][cc] += xv * v2;
        }
    }
#pragma unroll
    for (int k = 0; k < 3; k++) {
        float* dst = Mp + ((size_t)(blockIdx.y * 3 + k) * EMBED + d) * NCOL + c0 + cg;
        *(float4*)dst = make_float4(acc[k][0], acc[k][1], acc[k][2], acc[k][3]);
    }
}

// ---------------------------------------------------------------------------
// k_final: fused Mp-chunk reduction + epilogue (+ q finalization from qpart).
// out[b,o] = sum_{d,i} [ M0*(W0-W2) + M1*W1 + 2*M2*W2 ] + sum_d q[d]*bp[d,o] + pb
// ---------------------------------------------------------------------------
__global__ __launch_bounds__(256) void k_final(
    const float* __restrict__ Mp, const float* __restrict__ W,
    const float* __restrict__ bp, const float* __restrict__ qpart,
    const float* __restrict__ pb, float* __restrict__ out)
{
    const int b = blockIdx.x;
    const int tid = threadIdx.x;
    __shared__ float Ms[96][32];    // [k*32+d][i]
    __shared__ float qL[32];
    if (tid < 32) {
        float s = 0.f;
#pragma unroll
        for (int blk = 0; blk < 8; blk++) s += qpart[blk * EMBED + tid];
        qL[tid] = s;
    }
    for (int e = tid; e < 3072; e += 256) {
        const int kd = e >> 5;       // 0..95
        const int i  = e & 31;
        const int k  = kd >> 5;
        const int d  = kd & 31;
        float s = 0.f;
#pragma unroll
        for (int ch = 0; ch < 32; ch++)
            s += Mp[((size_t)(ch * 3 + k) * EMBED + d) * NCOL + b * INP + i];
        Ms[kd][i] = s;
    }
    __syncthreads();

    const int o  = tid & 31;
    const int ch = tid >> 5;    // 0..7
    __shared__ float part[8][32];
    float acc = 0.f;
#pragma unroll 4
    for (int t = ch * 128; t < (ch + 1) * 128; t++) {   // t over (d,i)
        const int d = t >> 5;
        const int i = t & 31;
        const float m0 = Ms[d][i];
        const float m1 = Ms[32 + d][i];
        const float m2 = Ms[64 + d][i];
        const float w0 = W[((size_t)(d * CHEB_K + 0) * INP + i) * OUTC + o];
        const float w1 = W[((size_t)(d * CHEB_K + 1) * INP + i) * OUTC + o];
        const float w2 = W[((size_t)(d * CHEB_K + 2) * INP + i) * OUTC + o];
        acc += m0 * w0 + m1 * w1 + (2.0f * m2 - m0) * w2;
    }
    part[ch][o] = acc;
    __syncthreads();
    if (ch == 0) {
        float s = 0.f;
#pragma unroll
        for (int cc = 0; cc < 8; cc++) s += part[cc][o];
#pragma unroll
        for (int d = 0; d < EMBED; d++) s += qL[d] * bp[d * OUTC + o];
        s += pb[0];
        out[b * OUTC + o] = s;
    }
}

// ---------------------------------------------------------------------------
extern "C" void kernel_launch(void* const* d_in, const int* in_sizes, int n_in,
                              void* d_out, int out_size, void* d_ws, size_t ws_size,
                              hipStream_t stream)
{
    const float* x     = (const float*)d_in[0];
    const float* adj   = (const float*)d_in[1];
    const float* gamma = (const float*)d_in[2];
    const float* Wp    = (const float*)d_in[3];
    const float* bp    = (const float*)d_in[4];
    const float* pw    = (const float*)d_in[5];
    const float* pb    = (const float*)d_in[6];
    const float* drop  = (const float*)d_in[7];
    float* out = (float*)d_out;

    float* ws = (float*)d_ws;
    float* Ehat  = ws;                                        // 4,194,304
    float* Vp    = Ehat + (size_t)N_NODES * N_NODES;          // 2,097,152 (aliased Mp)
    float* Mp    = Vp;
    float* Psum  = Vp   + (size_t)32 * N_NODES * EMBED;       // 65,536
    float* inv   = Psum + (size_t)32 * N_NODES;               // 2048
    float* U     = inv  + N_NODES;                            // 65,536
    float* Up    = U    + (size_t)N_NODES * EMBED;            // 65,536
    float* V1    = Up   + (size_t)N_NODES * EMBED;            // 65,536
    float* V1p   = V1   + (size_t)N_NODES * EMBED;            // 65,536
    float* V2    = V1p  + (size_t)N_NODES * EMBED;            // 65,536
    float* qpart = V2   + (size_t)N_NODES * EMBED;            // 256

    k_gram<<<dim3(32, 32), 256, 0, stream>>>(adj, gamma, drop, Ehat, Psum);
    k_inv<<<8, 256, 0, stream>>>(Psum, adj, pw, inv, U, Up, qpart);

    dim3 gv(16, 32);
    k_v<<<gv, 256, 0, stream>>>(Ehat, Up, Vp);
    k_vred<<<256, 256, 0, stream>>>(Vp, inv, V1, V1p, 1);
    k_v<<<gv, 256, 0, stream>>>(Ehat, V1p, Vp);
    k_vred<<<256, 256, 0, stream>>>(Vp, inv, V2, V2, 0);

    k_M<<<dim3(16, 32), 256, 0, stream>>>(x, U, V1, V2, Mp);
    k_final<<<B_BATCH, 256, 0, stream>>>(Mp, Wp, bp, qpart, pb, out);
}